// Round 16
// baseline (261.248 us; speedup 1.0000x reference)
//
#include <hip/hip_runtime.h>
#include <hip/hip_bf16.h>

typedef __attribute__((ext_vector_type(8))) __bf16 bf16x8;
typedef __attribute__((ext_vector_type(8))) short s16x8;
typedef __attribute__((ext_vector_type(4))) float f32x4;
typedef unsigned short u16;
typedef unsigned int u32;

static __device__ __forceinline__ float bf2f(u16 u) {
  union { unsigned int i; float f; } x;
  x.i = ((unsigned int)u) << 16;
  return x.f;
}
static __device__ __forceinline__ u16 f2bf(float f) {
  __hip_bfloat16 h = __float2bfloat16(f);
  return __builtin_bit_cast(u16, h);
}

// ---------------- fp32 -> bf16 convert, 3 tensors in one dispatch ------------
__global__ void cvt3_kernel(const float* __restrict__ s0, u16* __restrict__ d0, int n0,
                            const float* __restrict__ s1, u16* __restrict__ d1, int n1,
                            const float* __restrict__ s2, u16* __restrict__ d2, int n2) {
  const int stride = gridDim.x * blockDim.x;
  const int t0 = blockIdx.x * blockDim.x + threadIdx.x;
  for (int i = t0; i < n0; i += stride) {
    float4 f = reinterpret_cast<const float4*>(s0)[i];
    ushort4 u{f2bf(f.x), f2bf(f.y), f2bf(f.z), f2bf(f.w)};
    reinterpret_cast<ushort4*>(d0)[i] = u;
  }
  for (int i = t0; i < n1; i += stride) {
    float4 f = reinterpret_cast<const float4*>(s1)[i];
    ushort4 u{f2bf(f.x), f2bf(f.y), f2bf(f.z), f2bf(f.w)};
    reinterpret_cast<ushort4*>(d1)[i] = u;
  }
  for (int i = t0; i < n2; i += stride) {
    float4 f = reinterpret_cast<const float4*>(s2)[i];
    ushort4 u{f2bf(f.x), f2bf(f.y), f2bf(f.z), f2bf(f.w)};
    reinterpret_cast<ushort4*>(d2)[i] = u;
  }
}

// ======== 128x128 pipelined GEMM, BK=64, counted vmcnt, 2 blocks/CU =========
// Used for BOTH the QKV GEMM (grid 60x16) and the proj GEMM (grid 20x16).
// Proven structure (rounds 9-15 as proj): issue(t+1) first, counted vmcnt(8)
// (t+1's loads stay in flight across the barrier), raw barriers, XOR-swizzled
// conflict-free LDS, XCD-aware block swizzle.
template <typename OUT_T>
__global__ __launch_bounds__(256, 2) void gemm128p_bt(
    const u16* __restrict__ A, const u16* __restrict__ B,
    const float* __restrict__ bias, OUT_T* __restrict__ C,
    int M, int N, int K) {
  __shared__ u16 As[2][128 * 64];
  __shared__ u16 Bs[2][128 * 64];
  const int tid = threadIdx.x;     // 0..255
  const int w = tid >> 6;          // 0..3
  const int lane = tid & 63;
  const int g = lane >> 4, c = lane & 15;
  const int wm = w >> 1, wn = w & 1;  // 2 x 2 wave grid, wave tile 64x64
  const int nwg = gridDim.x * gridDim.y;
  const int flat = blockIdx.y * gridDim.x + blockIdx.x;
  const int swz = (flat & 7) * (nwg >> 3) + (flat >> 3);
  const int bx = swz % gridDim.x, by = swz / gridDim.x;
  const int row0 = by * 128, col0 = bx * 128;
  const int nt = K >> 6;  // BK = 64

  f32x4 acc[4][4] = {};

  auto issue = [&](const u16* __restrict__ base, int rb, int t, u16* lds) {
#pragma unroll
    for (int rr = 0; rr < 4; ++rr) {
      int q = rr * 256 + tid;
      int r = q >> 3;
      int cl = (q & 7) ^ (r & 7);
      const u16* gp = base + (size_t)(rb + r) * K + (t << 6) + cl * 8;
      __builtin_amdgcn_global_load_lds(
          (const __attribute__((address_space(1))) void*)gp,
          (__attribute__((address_space(3))) void*)(lds + q * 8), 16, 0, 0);
    }
  };

  issue(A, row0, 0, As[0]);
  issue(B, col0, 0, Bs[0]);

  int cur = 0;
  for (int t = 0; t < nt; ++t) {
    if (t + 1 < nt) {
      issue(A, row0, t + 1, As[cur ^ 1]);
      issue(B, col0, t + 1, Bs[cur ^ 1]);
      asm volatile("s_waitcnt vmcnt(8)" ::: "memory");
    } else {
      asm volatile("s_waitcnt vmcnt(0)" ::: "memory");
    }
    __builtin_amdgcn_s_barrier();

#pragma unroll
    for (int kk = 0; kk < 2; ++kk) {
      bf16x8 afr[4], bfr[4];
      const int p = (kk * 4 + g) ^ (c & 7);
#pragma unroll
      for (int mi = 0; mi < 4; ++mi) {
        int rowa = wm * 64 + mi * 16 + c;
        afr[mi] = *reinterpret_cast<const bf16x8*>(&As[cur][(rowa * 8 + p) * 8]);
      }
#pragma unroll
      for (int ni = 0; ni < 4; ++ni) {
        int rowb = wn * 64 + ni * 16 + c;
        bfr[ni] = *reinterpret_cast<const bf16x8*>(&Bs[cur][(rowb * 8 + p) * 8]);
      }
      __builtin_amdgcn_s_setprio(1);
#pragma unroll
      for (int mi = 0; mi < 4; ++mi)
#pragma unroll
        for (int ni = 0; ni < 4; ++ni)
          acc[mi][ni] = __builtin_amdgcn_mfma_f32_16x16x32_bf16(
              afr[mi], bfr[ni], acc[mi][ni], 0, 0, 0);
      __builtin_amdgcn_s_setprio(0);
      __builtin_amdgcn_s_barrier();
    }
    cur ^= 1;
  }

#pragma unroll
  for (int mi = 0; mi < 4; ++mi) {
#pragma unroll
    for (int ni = 0; ni < 4; ++ni) {
      int col = col0 + wn * 64 + ni * 16 + c;
      float bs = bias[col];
#pragma unroll
      for (int r = 0; r < 4; ++r) {
        int row = row0 + wm * 64 + mi * 16 + g * 4 + r;
        float v = acc[mi][ni][r] + bs;
        if constexpr (sizeof(OUT_T) == 2) {
          C[(size_t)row * N + col] = f2bf(v);
        } else {
          C[(size_t)row * N + col] = v;
        }
      }
    }
  }
}

// ---------------- Fused RoPE + V-transpose (round-14 exact) -----------------
__global__ __launch_bounds__(256) void ropev_kernel(
    const u16* __restrict__ qkv, const float* __restrict__ cosT,
    const float* __restrict__ sinT, u16* __restrict__ Qp, u16* __restrict__ Kp,
    u16* __restrict__ Vt) {
  __shared__ u16 Vs[80 * 136];
  const int h = blockIdx.y;
  const int tid = threadIdx.x;
  const int d = tid & 127;
  const int sh = tid >> 7;  // 0..1
  const float scale = 0.16129822f;  // 1/sqrt(80) * log2(e)
#pragma unroll
  for (int i = 0; i < 8; ++i) {
    const int s = blockIdx.x * 16 + i * 2 + sh;
    const size_t row = (size_t)s * 7680;
    if (d < 96) {
      float qo = 0.f, ko = 0.f;
      if (d < 80) {
        float q = bf2f(qkv[row + h * 80 + d]);
        float k = bf2f(qkv[row + 2560 + h * 80 + d]);
        if (d < 16) {
          float cs = cosT[s * 16 + d], sn = sinT[s * 16 + d];
          float q2 = bf2f(qkv[row + h * 80 + d + 16]);
          float k2 = bf2f(qkv[row + 2560 + h * 80 + d + 16]);
          qo = q * cs - q2 * sn;
          ko = k * cs - k2 * sn;
        } else if (d < 32) {
          float cs = cosT[s * 16 + d - 16], sn = sinT[s * 16 + d - 16];
          float q1 = bf2f(qkv[row + h * 80 + d - 16]);
          float k1 = bf2f(qkv[row + 2560 + h * 80 + d - 16]);
          qo = q1 * sn + q * cs;
          ko = k1 * sn + k * cs;
        } else {
          qo = q;
          ko = k;
        }
      }
      size_t o = ((size_t)h * 2048 + s) * 96 + d;
      Qp[o] = f2bf(qo * scale);
      Kp[o] = f2bf(ko);
    }
  }

  const int u = blockIdx.y * gridDim.x + blockIdx.x;
  if (u < 512) {
    const int s0 = (u & 15) * 128;
    const int hv = u >> 4;
    const int s = tid >> 1;
    const int h2 = tid & 1;
#pragma unroll
    for (int j = 0; j < 5; ++j) {
      s16x8 v = *reinterpret_cast<const s16x8*>(
          &qkv[(size_t)(s0 + s) * 7680 + 5120 + hv * 80 + h2 * 40 + j * 8]);
#pragma unroll
      for (int e = 0; e < 8; ++e)
        Vs[(h2 * 40 + j * 8 + e) * 136 + s] = (u16)v[e];
    }
    __syncthreads();
    for (int idx = tid; idx < 80 * 16; idx += 256) {
      int dd = idx >> 4, s8 = idx & 15;
      s16x8 v = *reinterpret_cast<const s16x8*>(&Vs[dd * 136 + s8 * 8]);
      *reinterpret_cast<s16x8*>(&Vt[((size_t)(hv * 80 + dd)) * 2048 + s0 + s8 * 8]) = v;
    }
  }
}

// ---------------- causal flash attention: 64 q-rows/block (round-15 exact) --
__global__ __launch_bounds__(256, 2) void attn_kernel(
    const u16* __restrict__ Qp, const u16* __restrict__ Kp,
    const u16* __restrict__ Vt, u16* __restrict__ O) {
  __shared__ u32 Plds[4][64 * 36];
  __shared__ float mbuf[4][4][16];
  const int tid = threadIdx.x;
  const int w = tid >> 6;
  const int lane = tid & 63;
  const int g = lane >> 4, c = lane & 15;
  const int f = blockIdx.x;        // 0..1023
  const int xcd = f & 7;
  const int k_ = f >> 3;           // 0..127
  const int h = (xcd << 2) | (k_ & 3);   // 4 heads per XCD
  const int pb = 31 - (k_ >> 2);         // 0..31, heavy blocks first
  const int q0 = pb * 64;
  const size_t hq = (size_t)h * 2048;
  u32* Pw = &Plds[w][0];

  bf16x8 bq[4][3];
#pragma unroll
  for (int qi = 0; qi < 4; ++qi)
#pragma unroll
    for (int ch = 0; ch < 3; ++ch)
      bq[qi][ch] = *reinterpret_cast<const bf16x8*>(
          &Qp[(hq + q0 + qi * 16 + c) * 96 + ch * 32 + g * 8]);

  f32x4 accO[4][5] = {};
  float mrow[4] = {-1e30f, -1e30f, -1e30f, -1e30f};
  float lrow[4] = {0.f, 0.f, 0.f, 0.f};

  const int nkb = pb + 1;  // KVBLK = 64
  for (int kbi = w; kbi < nkb; kbi += 4) {
    const int kb = kbi << 6;
    bf16x8 ak[4][3];
#pragma unroll
    for (int ki = 0; ki < 4; ++ki)
#pragma unroll
      for (int ch = 0; ch < 3; ++ch)
        ak[ki][ch] = *reinterpret_cast<const bf16x8*>(
            &Kp[(hq + kb + ki * 16 + c) * 96 + ch * 32 + g * 8]);

#pragma unroll
    for (int qh = 0; qh < 2; ++qh) {
      f32x4 SS[4][2] = {};
      __builtin_amdgcn_s_setprio(1);
#pragma unroll
      for (int ch = 0; ch < 3; ++ch)
#pragma unroll
        for (int ki = 0; ki < 4; ++ki)
#pragma unroll
          for (int j = 0; j < 2; ++j)
            SS[ki][j] = __builtin_amdgcn_mfma_f32_16x16x32_bf16(
                ak[ki][ch], bq[qh * 2 + j][ch], SS[ki][j], 0, 0, 0);
      __builtin_amdgcn_s_setprio(0);

      if (kbi == nkb - 1) {
#pragma unroll
        for (int ki = 0; ki < 4; ++ki)
#pragma unroll
          for (int j = 0; j < 2; ++j)
#pragma unroll
            for (int r = 0; r < 4; ++r) {
              int k = kb + ki * 16 + g * 4 + r;
              int q = q0 + (qh * 2 + j) * 16 + c;
              if (k > q) SS[ki][j][r] -= 14426.95f;
            }
      }

      float pmax[2];
      bool need = false;
#pragma unroll
      for (int j = 0; j < 2; ++j) {
        float m2 = SS[0][j][0];
#pragma unroll
        for (int ki = 0; ki < 4; ++ki)
#pragma unroll
          for (int r = 0; r < 4; ++r)
            if (ki | r) m2 = fmaxf(m2, SS[ki][j][r]);
        m2 = fmaxf(m2, __shfl_xor(m2, 16));
        m2 = fmaxf(m2, __shfl_xor(m2, 32));
        pmax[j] = m2;
        need = need || (m2 > mrow[qh * 2 + j] + 8.0f);
      }
      if (__any(need)) {
#pragma unroll
        for (int j = 0; j < 2; ++j) {
          int qi = qh * 2 + j;
          float mnew = fmaxf(mrow[qi], pmax[j]);
          float sc = __builtin_amdgcn_exp2f(mrow[qi] - mnew);
          lrow[qi] *= sc;
#pragma unroll
          for (int db = 0; db < 5; ++db) accO[qi][db] *= sc;
          mrow[qi] = mnew;
        }
      }
#pragma unroll
      for (int j = 0; j < 2; ++j) {
        int qi = qh * 2 + j;
        float rs = 0.f;
#pragma unroll
        for (int ki = 0; ki < 4; ++ki)
#pragma unroll
          for (int r = 0; r < 4; ++r) {
            float pv = __builtin_amdgcn_exp2f(SS[ki][j][r] - mrow[qi]);
            SS[ki][j][r] = pv;
            rs += pv;
          }
        rs += __shfl_xor(rs, 16);
        rs += __shfl_xor(rs, 32);
        lrow[qi] += rs;
      }
#pragma unroll
      for (int j = 0; j < 2; ++j)
#pragma unroll
        for (int ki = 0; ki < 4; ++ki)
#pragma unroll
          for (int r2 = 0; r2 < 2; ++r2) {
            u32 lo = f2bf(SS[ki][j][r2 * 2]);
            u32 hi = f2bf(SS[ki][j][r2 * 2 + 1]);
            Pw[((qh * 2 + j) * 16 + c) * 36 + ki * 8 + g * 2 + r2] =
                lo | (hi << 16);
          }
    }

    bf16x8 av[5][2];
#pragma unroll
    for (int db = 0; db < 5; ++db)
#pragma unroll
      for (int kc = 0; kc < 2; ++kc)
        av[db][kc] = *reinterpret_cast<const bf16x8*>(
            &Vt[((size_t)h * 80 + db * 16 + c) * 2048 + kb + kc * 32 + g * 8]);

    __builtin_amdgcn_s_setprio(1);
#pragma unroll
    for (int qi = 0; qi < 4; ++qi) {
      bf16x8 pa[2];
#pragma unroll
      for (int kc = 0; kc < 2; ++kc)
        pa[kc] = *reinterpret_cast<const bf16x8*>(
            &Pw[(qi * 16 + c) * 36 + kc * 16 + g * 4]);
#pragma unroll
      for (int kc = 0; kc < 2; ++kc)
#pragma unroll
        for (int db = 0; db < 5; ++db)
          accO[qi][db] = __builtin_amdgcn_mfma_f32_16x16x32_bf16(
              av[db][kc], pa[kc], accO[qi][db], 0, 0, 0);
    }
    __builtin_amdgcn_s_setprio(0);
  }

#pragma unroll
  for (int qi = 0; qi < 4; ++qi) mbuf[w][qi][c] = mrow[qi];
  __syncthreads();
#pragma unroll
  for (int qi = 0; qi < 4; ++qi) {
    float ms = fmaxf(fmaxf(mbuf[0][qi][c], mbuf[1][qi][c]),
                     fmaxf(mbuf[2][qi][c], mbuf[3][qi][c]));
    float fl = __builtin_amdgcn_exp2f(mrow[qi] - ms);
    lrow[qi] *= fl;
#pragma unroll
    for (int db = 0; db < 5; ++db) accO[qi][db] *= fl;
  }
  float* mg = (float*)&Plds[0][0] + lane * 84;
  if (w == 0) {
#pragma unroll
    for (int qi = 0; qi < 4; ++qi)
#pragma unroll
      for (int db = 0; db < 5; ++db)
        *reinterpret_cast<f32x4*>(mg + (qi * 5 + db) * 4) = accO[qi][db];
#pragma unroll
    for (int qi = 0; qi < 4; ++qi) mg[80 + qi] = lrow[qi];
  }
  __syncthreads();
  if (w == 1) {
#pragma unroll
    for (int qi = 0; qi < 4; ++qi)
#pragma unroll
      for (int db = 0; db < 5; ++db) {
        f32x4 t = *reinterpret_cast<f32x4*>(mg + (qi * 5 + db) * 4);
        *reinterpret_cast<f32x4*>(mg + (qi * 5 + db) * 4) = t + accO[qi][db];
      }
#pragma unroll
    for (int qi = 0; qi < 4; ++qi) mg[80 + qi] += lrow[qi];
  }
  __syncthreads();
  if (w == 2) {
#pragma unroll
    for (int qi = 0; qi < 4; ++qi)
#pragma unroll
      for (int db = 0; db < 5; ++db) {
        f32x4 t = *reinterpret_cast<f32x4*>(mg + (qi * 5 + db) * 4);
        *reinterpret_cast<f32x4*>(mg + (qi * 5 + db) * 4) = t + accO[qi][db];
      }
#pragma unroll
    for (int qi = 0; qi < 4; ++qi) mg[80 + qi] += lrow[qi];
  }
  __syncthreads();
  if (w == 3) {
#pragma unroll
    for (int qi = 0; qi < 4; ++qi) {
      float lf = 1.0f / (mg[80 + qi] + lrow[qi]);
#pragma unroll
      for (int db = 0; db < 5; ++db) {
        f32x4 t = *reinterpret_cast<f32x4*>(mg + (qi * 5 + db) * 4);
        t = t + accO[qi][db];
        ushort4 o4;
        o4.x = f2bf(t[0] * lf);
        o4.y = f2bf(t[1] * lf);
        o4.z = f2bf(t[2] * lf);
        o4.w = f2bf(t[3] * lf);
        *reinterpret_cast<ushort4*>(
            &O[(size_t)(q0 + qi * 16 + c) * 2560 + h * 80 + db * 16 + g * 4]) = o4;
      }
    }
  }
}

extern "C" void kernel_launch(void* const* d_in, const int* in_sizes, int n_in,
                              void* d_out, int out_size, void* d_ws, size_t ws_size,
                              hipStream_t stream) {
  const float* hs = (const float*)d_in[0];
  const float* Wqkv_w = (const float*)d_in[1];
  const float* Wqkv_b = (const float*)d_in[2];
  const float* out_w = (const float*)d_in[3];
  const float* out_b = (const float*)d_in[4];
  const float* cosT = (const float*)d_in[5];
  const float* sinT = (const float*)d_in[6];
  float* out = (float*)d_out;

  u16* ws = (u16*)d_ws;
  u16* hsb = ws;
  u16* wqkvb = hsb + (size_t)2048 * 2560;
  u16* outwb = wqkvb + (size_t)7680 * 2560;
  u16* qkv = outwb + (size_t)2560 * 2560;
  u16* Qp = qkv + (size_t)2048 * 7680;
  u16* Kp = Qp + (size_t)32 * 2048 * 96;
  u16* Vt = Kp + (size_t)32 * 2048 * 96;
  u16* attn = qkv;  // reuse

  cvt3_kernel<<<dim3(2048), dim3(256), 0, stream>>>(
      hs, hsb, 5242880 / 4, Wqkv_w, wqkvb, 19660800 / 4, out_w, outwb, 6553600 / 4);

  gemm128p_bt<u16><<<dim3(60, 16), dim3(256), 0, stream>>>(
      hsb, wqkvb, Wqkv_b, qkv, 2048, 7680, 2560);
  ropev_kernel<<<dim3(128, 32), dim3(256), 0, stream>>>(qkv, cosT, sinT, Qp, Kp, Vt);
  attn_kernel<<<dim3(1024), dim3(256), 0, stream>>>(Qp, Kp, Vt, attn);
  gemm128p_bt<float><<<dim3(20, 16), dim3(256), 0, stream>>>(attn, outwb, out_b, out,
                                                             2048, 2560, 2560);
}

// Round 17
// 244.696 us; speedup vs baseline: 1.0676x; 1.0676x over previous
//
#include <hip/hip_runtime.h>
#include <hip/hip_bf16.h>

typedef __attribute__((ext_vector_type(8))) __bf16 bf16x8;
typedef __attribute__((ext_vector_type(8))) short s16x8;
typedef __attribute__((ext_vector_type(4))) float f32x4;
typedef unsigned short u16;
typedef unsigned int u32;

static __device__ __forceinline__ float bf2f(u16 u) {
  union { unsigned int i; float f; } x;
  x.i = ((unsigned int)u) << 16;
  return x.f;
}
static __device__ __forceinline__ u16 f2bf(float f) {
  __hip_bfloat16 h = __float2bfloat16(f);
  return __builtin_bit_cast(u16, h);
}

// ---------------- fp32 -> bf16 convert, 3 tensors in one dispatch ------------
__global__ void cvt3_kernel(const float* __restrict__ s0, u16* __restrict__ d0, int n0,
                            const float* __restrict__ s1, u16* __restrict__ d1, int n1,
                            const float* __restrict__ s2, u16* __restrict__ d2, int n2) {
  const int stride = gridDim.x * blockDim.x;
  const int t0 = blockIdx.x * blockDim.x + threadIdx.x;
  for (int i = t0; i < n0; i += stride) {
    float4 f = reinterpret_cast<const float4*>(s0)[i];
    ushort4 u{f2bf(f.x), f2bf(f.y), f2bf(f.z), f2bf(f.w)};
    reinterpret_cast<ushort4*>(d0)[i] = u;
  }
  for (int i = t0; i < n1; i += stride) {
    float4 f = reinterpret_cast<const float4*>(s1)[i];
    ushort4 u{f2bf(f.x), f2bf(f.y), f2bf(f.z), f2bf(f.w)};
    reinterpret_cast<ushort4*>(d1)[i] = u;
  }
  for (int i = t0; i < n2; i += stride) {
    float4 f = reinterpret_cast<const float4*>(s2)[i];
    ushort4 u{f2bf(f.x), f2bf(f.y), f2bf(f.z), f2bf(f.w)};
    reinterpret_cast<ushort4*>(d2)[i] = u;
  }
}

// ======== QKV GEMM: 128x256 tile, BK=32, double buffer, 2 blocks/CU =========
// Best measured (~97us, 0 conflicts, occupancy 36%). QKV tile bracketing
// complete: 256²=97, 128x256=97, 128²=110 (A-refetch BW-bound); schedule
// variants 97-115 -> ~97us is the practical ceiling for this shape.
template <typename OUT_T>
__global__ __launch_bounds__(512, 4) void gemm128x256_bt(
    const u16* __restrict__ A, const u16* __restrict__ B,
    const float* __restrict__ bias, OUT_T* __restrict__ C,
    int M, int N, int K) {
  __shared__ u16 As[2][128 * 32];
  __shared__ u16 Bs[2][256 * 32];
  const int tid = threadIdx.x;     // 0..511
  const int w = tid >> 6;          // 0..7
  const int lane = tid & 63;
  const int g = lane >> 4, c = lane & 15;
  const int wm = w >> 2, wn = w & 3;  // 2 x 4 wave grid, wave tile 64x64
  const int nwg = gridDim.x * gridDim.y;
  const int flat = blockIdx.y * gridDim.x + blockIdx.x;
  const int swz = (flat & 7) * (nwg >> 3) + (flat >> 3);
  const int bx = swz % gridDim.x, by = swz / gridDim.x;
  const int row0 = by * 128, col0 = bx * 256;
  const int nt = K >> 5;  // BK = 32

  f32x4 acc[4][4] = {};

  auto issueA = [&](int t, u16* lds) {
    int q = tid;                   // slot: row = q>>2, phys chunk = q&3
    int r = q >> 2;
    int cl = (q & 3) ^ ((r >> 1) & 3);
    const u16* gp = A + (size_t)(row0 + r) * K + (t << 5) + cl * 8;
    __builtin_amdgcn_global_load_lds(
        (const __attribute__((address_space(1))) void*)gp,
        (__attribute__((address_space(3))) void*)(lds + q * 8), 16, 0, 0);
  };
  auto issueB = [&](int t, u16* lds) {
#pragma unroll
    for (int rr = 0; rr < 2; ++rr) {
      int q = rr * 512 + tid;
      int r = q >> 2;
      int cl = (q & 3) ^ ((r >> 1) & 3);
      const u16* gp = B + (size_t)(col0 + r) * K + (t << 5) + cl * 8;
      __builtin_amdgcn_global_load_lds(
          (const __attribute__((address_space(1))) void*)gp,
          (__attribute__((address_space(3))) void*)(lds + q * 8), 16, 0, 0);
    }
  };

  issueA(0, As[0]);
  issueB(0, Bs[0]);

  int cur = 0;
  for (int t = 0; t < nt; ++t) {
    if (t + 1 < nt) {
      issueA(t + 1, As[cur ^ 1]);
      issueB(t + 1, Bs[cur ^ 1]);
      asm volatile("s_waitcnt vmcnt(3)" ::: "memory");  // tile t's 3 retired
    } else {
      asm volatile("s_waitcnt vmcnt(0)" ::: "memory");
    }
    __builtin_amdgcn_s_barrier();

    bf16x8 afr[4], bfr[4];
#pragma unroll
    for (int mi = 0; mi < 4; ++mi) {
      int rowa = wm * 64 + mi * 16 + c;
      int p = g ^ ((rowa >> 1) & 3);
      afr[mi] = *reinterpret_cast<const bf16x8*>(&As[cur][(rowa * 4 + p) * 8]);
    }
#pragma unroll
    for (int ni = 0; ni < 4; ++ni) {
      int rowb = wn * 64 + ni * 16 + c;
      int p = g ^ ((rowb >> 1) & 3);
      bfr[ni] = *reinterpret_cast<const bf16x8*>(&Bs[cur][(rowb * 4 + p) * 8]);
    }
    __builtin_amdgcn_s_setprio(1);
#pragma unroll
    for (int mi = 0; mi < 4; ++mi)
#pragma unroll
      for (int ni = 0; ni < 4; ++ni)
        acc[mi][ni] = __builtin_amdgcn_mfma_f32_16x16x32_bf16(
            afr[mi], bfr[ni], acc[mi][ni], 0, 0, 0);
    __builtin_amdgcn_s_setprio(0);
    __builtin_amdgcn_s_barrier();  // reads done before next iter's DMA
    cur ^= 1;
  }

#pragma unroll
  for (int mi = 0; mi < 4; ++mi) {
#pragma unroll
    for (int ni = 0; ni < 4; ++ni) {
      int col = col0 + wn * 64 + ni * 16 + c;
      float bs = bias[col];
#pragma unroll
      for (int r = 0; r < 4; ++r) {
        int row = row0 + wm * 64 + mi * 16 + g * 4 + r;
        float v = acc[mi][ni][r] + bs;
        if constexpr (sizeof(OUT_T) == 2) {
          C[(size_t)row * N + col] = f2bf(v);
        } else {
          C[(size_t)row * N + col] = v;
        }
      }
    }
  }
}

// ======== 128x128 pipelined GEMM (proj) — proven ============================
template <typename OUT_T>
__global__ __launch_bounds__(256, 2) void gemm128p_bt(
    const u16* __restrict__ A, const u16* __restrict__ B,
    const float* __restrict__ bias, OUT_T* __restrict__ C,
    int M, int N, int K) {
  __shared__ u16 As[2][128 * 64];
  __shared__ u16 Bs[2][128 * 64];
  const int tid = threadIdx.x;     // 0..255
  const int w = tid >> 6;          // 0..3
  const int lane = tid & 63;
  const int g = lane >> 4, c = lane & 15;
  const int wm = w >> 1, wn = w & 1;  // 2 x 2 wave grid, wave tile 64x64
  const int nwg = gridDim.x * gridDim.y;
  const int flat = blockIdx.y * gridDim.x + blockIdx.x;
  const int swz = (flat & 7) * (nwg >> 3) + (flat >> 3);
  const int bx = swz % gridDim.x, by = swz / gridDim.x;
  const int row0 = by * 128, col0 = bx * 128;
  const int nt = K >> 6;  // BK = 64

  f32x4 acc[4][4] = {};

  auto issue = [&](const u16* __restrict__ base, int rb, int t, u16* lds) {
#pragma unroll
    for (int rr = 0; rr < 4; ++rr) {
      int q = rr * 256 + tid;
      int r = q >> 3;
      int cl = (q & 7) ^ (r & 7);
      const u16* gp = base + (size_t)(rb + r) * K + (t << 6) + cl * 8;
      __builtin_amdgcn_global_load_lds(
          (const __attribute__((address_space(1))) void*)gp,
          (__attribute__((address_space(3))) void*)(lds + q * 8), 16, 0, 0);
    }
  };

  issue(A, row0, 0, As[0]);
  issue(B, col0, 0, Bs[0]);

  int cur = 0;
  for (int t = 0; t < nt; ++t) {
    if (t + 1 < nt) {
      issue(A, row0, t + 1, As[cur ^ 1]);
      issue(B, col0, t + 1, Bs[cur ^ 1]);
      asm volatile("s_waitcnt vmcnt(8)" ::: "memory");
    } else {
      asm volatile("s_waitcnt vmcnt(0)" ::: "memory");
    }
    __builtin_amdgcn_s_barrier();

#pragma unroll
    for (int kk = 0; kk < 2; ++kk) {
      bf16x8 afr[4], bfr[4];
      const int p = (kk * 4 + g) ^ (c & 7);
#pragma unroll
      for (int mi = 0; mi < 4; ++mi) {
        int rowa = wm * 64 + mi * 16 + c;
        afr[mi] = *reinterpret_cast<const bf16x8*>(&As[cur][(rowa * 8 + p) * 8]);
      }
#pragma unroll
      for (int ni = 0; ni < 4; ++ni) {
        int rowb = wn * 64 + ni * 16 + c;
        bfr[ni] = *reinterpret_cast<const bf16x8*>(&Bs[cur][(rowb * 8 + p) * 8]);
      }
      __builtin_amdgcn_s_setprio(1);
#pragma unroll
      for (int mi = 0; mi < 4; ++mi)
#pragma unroll
        for (int ni = 0; ni < 4; ++ni)
          acc[mi][ni] = __builtin_amdgcn_mfma_f32_16x16x32_bf16(
              afr[mi], bfr[ni], acc[mi][ni], 0, 0, 0);
      __builtin_amdgcn_s_setprio(0);
      __builtin_amdgcn_s_barrier();
    }
    cur ^= 1;
  }

#pragma unroll
  for (int mi = 0; mi < 4; ++mi) {
#pragma unroll
    for (int ni = 0; ni < 4; ++ni) {
      int col = col0 + wn * 64 + ni * 16 + c;
      float bs = bias[col];
#pragma unroll
      for (int r = 0; r < 4; ++r) {
        int row = row0 + wm * 64 + mi * 16 + g * 4 + r;
        float v = acc[mi][ni][r] + bs;
        if constexpr (sizeof(OUT_T) == 2) {
          C[(size_t)row * N + col] = f2bf(v);
        } else {
          C[(size_t)row * N + col] = v;
        }
      }
    }
  }
}

// ---------------- Fused RoPE + V-transpose ----------------------------------
__global__ __launch_bounds__(256) void ropev_kernel(
    const u16* __restrict__ qkv, const float* __restrict__ cosT,
    const float* __restrict__ sinT, u16* __restrict__ Qp, u16* __restrict__ Kp,
    u16* __restrict__ Vt) {
  __shared__ u16 Vs[80 * 136];
  const int h = blockIdx.y;
  const int tid = threadIdx.x;
  const int d = tid & 127;
  const int sh = tid >> 7;  // 0..1
  const float scale = 0.16129822f;  // 1/sqrt(80) * log2(e)
#pragma unroll
  for (int i = 0; i < 8; ++i) {
    const int s = blockIdx.x * 16 + i * 2 + sh;
    const size_t row = (size_t)s * 7680;
    if (d < 96) {
      float qo = 0.f, ko = 0.f;
      if (d < 80) {
        float q = bf2f(qkv[row + h * 80 + d]);
        float k = bf2f(qkv[row + 2560 + h * 80 + d]);
        if (d < 16) {
          float cs = cosT[s * 16 + d], sn = sinT[s * 16 + d];
          float q2 = bf2f(qkv[row + h * 80 + d + 16]);
          float k2 = bf2f(qkv[row + 2560 + h * 80 + d + 16]);
          qo = q * cs - q2 * sn;
          ko = k * cs - k2 * sn;
        } else if (d < 32) {
          float cs = cosT[s * 16 + d - 16], sn = sinT[s * 16 + d - 16];
          float q1 = bf2f(qkv[row + h * 80 + d - 16]);
          float k1 = bf2f(qkv[row + 2560 + h * 80 + d - 16]);
          qo = q1 * sn + q * cs;
          ko = k1 * sn + k * cs;
        } else {
          qo = q;
          ko = k;
        }
      }
      size_t o = ((size_t)h * 2048 + s) * 96 + d;
      Qp[o] = f2bf(qo * scale);
      Kp[o] = f2bf(ko);
    }
  }

  const int u = blockIdx.y * gridDim.x + blockIdx.x;
  if (u < 512) {
    const int s0 = (u & 15) * 128;
    const int hv = u >> 4;
    const int s = tid >> 1;
    const int h2 = tid & 1;
#pragma unroll
    for (int j = 0; j < 5; ++j) {
      s16x8 v = *reinterpret_cast<const s16x8*>(
          &qkv[(size_t)(s0 + s) * 7680 + 5120 + hv * 80 + h2 * 40 + j * 8]);
#pragma unroll
      for (int e = 0; e < 8; ++e)
        Vs[(h2 * 40 + j * 8 + e) * 136 + s] = (u16)v[e];
    }
    __syncthreads();
    for (int idx = tid; idx < 80 * 16; idx += 256) {
      int dd = idx >> 4, s8 = idx & 15;
      s16x8 v = *reinterpret_cast<const s16x8*>(&Vs[dd * 136 + s8 * 8]);
      *reinterpret_cast<s16x8*>(&Vt[((size_t)(hv * 80 + dd)) * 2048 + s0 + s8 * 8]) = v;
    }
  }
}

// ---------------- causal flash attention: 64 q-rows/block, 4-wave k-split ----
__global__ __launch_bounds__(256, 2) void attn_kernel(
    const u16* __restrict__ Qp, const u16* __restrict__ Kp,
    const u16* __restrict__ Vt, u16* __restrict__ O) {
  __shared__ u32 Plds[4][64 * 36];
  __shared__ float mbuf[4][4][16];
  const int tid = threadIdx.x;
  const int w = tid >> 6;
  const int lane = tid & 63;
  const int g = lane >> 4, c = lane & 15;
  const int f = blockIdx.x;        // 0..1023
  const int xcd = f & 7;
  const int k_ = f >> 3;           // 0..127
  const int h = (xcd << 2) | (k_ & 3);   // 4 heads per XCD
  const int pb = 31 - (k_ >> 2);         // 0..31, heavy blocks first
  const int q0 = pb * 64;
  const size_t hq = (size_t)h * 2048;
  u32* Pw = &Plds[w][0];

  bf16x8 bq[4][3];
#pragma unroll
  for (int qi = 0; qi < 4; ++qi)
#pragma unroll
    for (int ch = 0; ch < 3; ++ch)
      bq[qi][ch] = *reinterpret_cast<const bf16x8*>(
          &Qp[(hq + q0 + qi * 16 + c) * 96 + ch * 32 + g * 8]);

  f32x4 accO[4][5] = {};
  float mrow[4] = {-1e30f, -1e30f, -1e30f, -1e30f};
  float lrow[4] = {0.f, 0.f, 0.f, 0.f};

  const int nkb = pb + 1;  // KVBLK = 64
  for (int kbi = w; kbi < nkb; kbi += 4) {
    const int kb = kbi << 6;
    bf16x8 ak[4][3];
#pragma unroll
    for (int ki = 0; ki < 4; ++ki)
#pragma unroll
      for (int ch = 0; ch < 3; ++ch)
        ak[ki][ch] = *reinterpret_cast<const bf16x8*>(
            &Kp[(hq + kb + ki * 16 + c) * 96 + ch * 32 + g * 8]);

#pragma unroll
    for (int qh = 0; qh < 2; ++qh) {
      f32x4 SS[4][2] = {};
      __builtin_amdgcn_s_setprio(1);
#pragma unroll
      for (int ch = 0; ch < 3; ++ch)
#pragma unroll
        for (int ki = 0; ki < 4; ++ki)
#pragma unroll
          for (int j = 0; j < 2; ++j)
            SS[ki][j] = __builtin_amdgcn_mfma_f32_16x16x32_bf16(
                ak[ki][ch], bq[qh * 2 + j][ch], SS[ki][j], 0, 0, 0);
      __builtin_amdgcn_s_setprio(0);

      if (kbi == nkb - 1) {
#pragma unroll
        for (int ki = 0; ki < 4; ++ki)
#pragma unroll
          for (int j = 0; j < 2; ++j)
#pragma unroll
            for (int r = 0; r < 4; ++r) {
              int k = kb + ki * 16 + g * 4 + r;
              int q = q0 + (qh * 2 + j) * 16 + c;
              if (k > q) SS[ki][j][r] -= 14426.95f;
            }
      }

      float pmax[2];
      bool need = false;
#pragma unroll
      for (int j = 0; j < 2; ++j) {
        float m2 = SS[0][j][0];
#pragma unroll
        for (int ki = 0; ki < 4; ++ki)
#pragma unroll
          for (int r = 0; r < 4; ++r)
            if (ki | r) m2 = fmaxf(m2, SS[ki][j][r]);
        m2 = fmaxf(m2, __shfl_xor(m2, 16));
        m2 = fmaxf(m2, __shfl_xor(m2, 32));
        pmax[j] = m2;
        need = need || (m2 > mrow[qh * 2 + j] + 8.0f);
      }
      if (__any(need)) {
#pragma unroll
        for (int j = 0; j < 2; ++j) {
          int qi = qh * 2 + j;
          float mnew = fmaxf(mrow[qi], pmax[j]);
          float sc = __builtin_amdgcn_exp2f(mrow[qi] - mnew);
          lrow[qi] *= sc;
#pragma unroll
          for (int db = 0; db < 5; ++db) accO[qi][db] *= sc;
          mrow[qi] = mnew;
        }
      }
#pragma unroll
      for (int j = 0; j < 2; ++j) {
        int qi = qh * 2 + j;
        float rs = 0.f;
#pragma unroll
        for (int ki = 0; ki < 4; ++ki)
#pragma unroll
          for (int r = 0; r < 4; ++r) {
            float pv = __builtin_amdgcn_exp2f(SS[ki][j][r] - mrow[qi]);
            SS[ki][j][r] = pv;
            rs += pv;
          }
        rs += __shfl_xor(rs, 16);
        rs += __shfl_xor(rs, 32);
        lrow[qi] += rs;
      }
#pragma unroll
      for (int j = 0; j < 2; ++j)
#pragma unroll
        for (int ki = 0; ki < 4; ++ki)
#pragma unroll
          for (int r2 = 0; r2 < 2; ++r2) {
            u32 lo = f2bf(SS[ki][j][r2 * 2]);
            u32 hi = f2bf(SS[ki][j][r2 * 2 + 1]);
            Pw[((qh * 2 + j) * 16 + c) * 36 + ki * 8 + g * 2 + r2] =
                lo | (hi << 16);
          }
    }

    bf16x8 av[5][2];
#pragma unroll
    for (int db = 0; db < 5; ++db)
#pragma unroll
      for (int kc = 0; kc < 2; ++kc)
        av[db][kc] = *reinterpret_cast<const bf16x8*>(
            &Vt[((size_t)h * 80 + db * 16 + c) * 2048 + kb + kc * 32 + g * 8]);

    __builtin_amdgcn_s_setprio(1);
#pragma unroll
    for (int qi = 0; qi < 4; ++qi) {
      bf16x8 pa[2];
#pragma unroll
      for (int kc = 0; kc < 2; ++kc)
        pa[kc] = *reinterpret_cast<const bf16x8*>(
            &Pw[(qi * 16 + c) * 36 + kc * 16 + g * 4]);
#pragma unroll
      for (int kc = 0; kc < 2; ++kc)
#pragma unroll
        for (int db = 0; db < 5; ++db)
          accO[qi][db] = __builtin_amdgcn_mfma_f32_16x16x32_bf16(
              av[db][kc], pa[kc], accO[qi][db], 0, 0, 0);
    }
    __builtin_amdgcn_s_setprio(0);
  }

#pragma unroll
  for (int qi = 0; qi < 4; ++qi) mbuf[w][qi][c] = mrow[qi];
  __syncthreads();
#pragma unroll
  for (int qi = 0; qi < 4; ++qi) {
    float ms = fmaxf(fmaxf(mbuf[0][qi][c], mbuf[1][qi][c]),
                     fmaxf(mbuf[2][qi][c], mbuf[3][qi][c]));
    float fl = __builtin_amdgcn_exp2f(mrow[qi] - ms);
    lrow[qi] *= fl;
#pragma unroll
    for (int db = 0; db < 5; ++db) accO[qi][db] *= fl;
  }
  float* mg = (float*)&Plds[0][0] + lane * 84;
  if (w == 0) {
#pragma unroll
    for (int qi = 0; qi < 4; ++qi)
#pragma unroll
      for (int db = 0; db < 5; ++db)
        *reinterpret_cast<f32x4*>(mg + (qi * 5 + db) * 4) = accO[qi][db];
#pragma unroll
    for (int qi = 0; qi < 4; ++qi) mg[80 + qi] = lrow[qi];
  }
  __syncthreads();
  if (w == 1) {
#pragma unroll
    for (int qi = 0; qi < 4; ++qi)
#pragma unroll
      for (int db = 0; db < 5; ++db) {
        f32x4 t = *reinterpret_cast<f32x4*>(mg + (qi * 5 + db) * 4);
        *reinterpret_cast<f32x4*>(mg + (qi * 5 + db) * 4) = t + accO[qi][db];
      }
#pragma unroll
    for (int qi = 0; qi < 4; ++qi) mg[80 + qi] += lrow[qi];
  }
  __syncthreads();
  if (w == 2) {
#pragma unroll
    for (int qi = 0; qi < 4; ++qi)
#pragma unroll
      for (int db = 0; db < 5; ++db) {
        f32x4 t = *reinterpret_cast<f32x4*>(mg + (qi * 5 + db) * 4);
        *reinterpret_cast<f32x4*>(mg + (qi * 5 + db) * 4) = t + accO[qi][db];
      }
#pragma unroll
    for (int qi = 0; qi < 4; ++qi) mg[80 + qi] += lrow[qi];
  }
  __syncthreads();
  if (w == 3) {
#pragma unroll
    for (int qi = 0; qi < 4; ++qi) {
      float lf = 1.0f / (mg[80 + qi] + lrow[qi]);
#pragma unroll
      for (int db = 0; db < 5; ++db) {
        f32x4 t = *reinterpret_cast<f32x4*>(mg + (qi * 5 + db) * 4);
        t = t + accO[qi][db];
        ushort4 o4;
        o4.x = f2bf(t[0] * lf);
        o4.y = f2bf(t[1] * lf);
        o4.z = f2bf(t[2] * lf);
        o4.w = f2bf(t[3] * lf);
        *reinterpret_cast<ushort4*>(
            &O[(size_t)(q0 + qi * 16 + c) * 2560 + h * 80 + db * 16 + g * 4]) = o4;
      }
    }
  }
}

extern "C" void kernel_launch(void* const* d_in, const int* in_sizes, int n_in,
                              void* d_out, int out_size, void* d_ws, size_t ws_size,
                              hipStream_t stream) {
  const float* hs = (const float*)d_in[0];
  const float* Wqkv_w = (const float*)d_in[1];
  const float* Wqkv_b = (const float*)d_in[2];
  const float* out_w = (const float*)d_in[3];
  const float* out_b = (const float*)d_in[4];
  const float* cosT = (const float*)d_in[5];
  const float* sinT = (const float*)d_in[6];
  float* out = (float*)d_out;

  u16* ws = (u16*)d_ws;
  u16* hsb = ws;
  u16* wqkvb = hsb + (size_t)2048 * 2560;
  u16* outwb = wqkvb + (size_t)7680 * 2560;
  u16* qkv = outwb + (size_t)2560 * 2560;
  u16* Qp = qkv + (size_t)2048 * 7680;
  u16* Kp = Qp + (size_t)32 * 2048 * 96;
  u16* Vt = Kp + (size_t)32 * 2048 * 96;
  u16* attn = qkv;  // reuse

  cvt3_kernel<<<dim3(2048), dim3(256), 0, stream>>>(
      hs, hsb, 5242880 / 4, Wqkv_w, wqkvb, 19660800 / 4, out_w, outwb, 6553600 / 4);

  gemm128x256_bt<u16><<<dim3(30, 16), dim3(512), 0, stream>>>(
      hsb, wqkvb, Wqkv_b, qkv, 2048, 7680, 2560);
  ropev_kernel<<<dim3(128, 32), dim3(256), 0, stream>>>(qkv, cosT, sinT, Qp, Kp, Vt);
  attn_kernel<<<dim3(1024), dim3(256), 0, stream>>>(Qp, Kp, Vt, attn);
  gemm128p_bt<float><<<dim3(20, 16), dim3(256), 0, stream>>>(attn, outwb, out_b, out,
                                                             2048, 2560, 2560);
}